// Round 14
// baseline (228.344 us; speedup 1.0000x reference)
//
#include <hip/hip_runtime.h>
#include <hip/hip_bf16.h>

typedef unsigned short u16;
typedef short bf16x8 __attribute__((ext_vector_type(8)));
typedef float f32x4 __attribute__((ext_vector_type(4)));
typedef unsigned long long u64;

#define B_ 4
#define S_ 1024
#define E_ 1024
#define H_ 16
#define FF_ 4096
#define D_ 64
#define M_ 4096  /* B*S */

__device__ __forceinline__ u16 f2bf(float f) {
  unsigned int u = __builtin_bit_cast(unsigned int, f);
  u += 0x7fffu + ((u >> 16) & 1u);   // RNE
  return (u16)(u >> 16);
}
__device__ __forceinline__ float bf2f(u16 v) {
  unsigned int u = ((unsigned int)v) << 16;
  return __builtin_bit_cast(float, u);
}

__device__ __forceinline__ void gld_lds16(const void* g, void* l) {
  __builtin_amdgcn_global_load_lds((__attribute__((address_space(1))) void*)g,
                                   (__attribute__((address_space(3))) void*)l,
                                   16, 0, 0);
}

// ---------------------------------------------------------------------------
// Fused prologue: [0,12288) weight cast+transpose; [12288,16384) LN1;
// [16384,20480) mask->bitmask + gnn->bf16.
// ---------------------------------------------------------------------------
__global__ void __launch_bounds__(256) pre_kernel(
    const float* __restrict__ wq, const float* __restrict__ wk,
    const float* __restrict__ wv, const float* __restrict__ wo,
    const float* __restrict__ w1, const float* __restrict__ w2,
    u16* __restrict__ wt,
    const float* __restrict__ x, const float* __restrict__ g1,
    const float* __restrict__ b1, u16* __restrict__ nx,
    const float* __restrict__ mask, const float* __restrict__ gnn,
    u64* __restrict__ mb, u16* __restrict__ gnnbf) {
  __shared__ __attribute__((aligned(16))) float smem_f[1088];
  int bid = blockIdx.x;
  int t = threadIdx.x;
  if (bid < 12288) {
    const float* src; u16* dst; int K, N; int local;
    if (bid < 4096) {
      int wsel = bid >> 10; local = bid & 1023; K = 1024; N = 1024;
      src = wsel == 0 ? wq : wsel == 1 ? wk : wsel == 2 ? wv : wo;
      dst = wt + (size_t)wsel * 1024 * 1024;
    } else if (bid < 8192) {
      local = bid - 4096; K = 1024; N = 4096; src = w1;
      dst = wt + (size_t)4 * 1024 * 1024;
    } else {
      local = bid - 8192; K = 4096; N = 1024; src = w2;
      dst = wt + (size_t)8 * 1024 * 1024;
    }
    int tiles_n = N >> 5;
    int n0 = (local % tiles_n) << 5, k0 = (local / tiles_n) << 5;
    float (*tl)[33] = reinterpret_cast<float(*)[33]>(smem_f);
    int tx = t & 31, ty = t >> 5;
#pragma unroll
    for (int i = 0; i < 4; ++i)
      tl[ty + i * 8][tx] = src[(size_t)(k0 + ty + i * 8) * N + n0 + tx];
    __syncthreads();
#pragma unroll
    for (int i = 0; i < 4; ++i)
      dst[(size_t)(n0 + ty + i * 8) * K + k0 + tx] = f2bf(tl[tx][ty + i * 8]);
  } else if (bid < 16384) {
    int row = bid - 12288;
    const float* xr = x + (size_t)row * 1024;
    float4 v = *(const float4*)(xr + t * 4);
    float s = v.x + v.y + v.z + v.w;
    float q = v.x * v.x + v.y * v.y + v.z * v.z + v.w * v.w;
#pragma unroll
    for (int off = 1; off < 64; off <<= 1) {
      s += __shfl_xor(s, off);
      q += __shfl_xor(q, off);
    }
    float* sb = smem_f;
    float* qb = smem_f + 4;
    int w = t >> 6, l = t & 63;
    if (l == 0) { sb[w] = s; qb[w] = q; }
    __syncthreads();
    s = sb[0] + sb[1] + sb[2] + sb[3];
    q = qb[0] + qb[1] + qb[2] + qb[3];
    float mean = s * (1.f / 1024.f);
    float var = q * (1.f / 1024.f) - mean * mean;
    float rs = rsqrtf(var + 1e-5f);
    float4 gv = *(const float4*)(g1 + t * 4);
    float4 bv = *(const float4*)(b1 + t * 4);
    ushort4 o;
    o.x = f2bf((v.x - mean) * rs * gv.x + bv.x);
    o.y = f2bf((v.y - mean) * rs * gv.y + bv.y);
    o.z = f2bf((v.z - mean) * rs * gv.z + bv.z);
    o.w = f2bf((v.w - mean) * rs * gv.w + bv.w);
    *(ushort4*)(nx + (size_t)row * 1024 + t * 4) = o;
  } else {
    int row = bid - 16384;
    int b = row >> 10, q = row & 1023;
    const float* mp = mask + ((size_t)row << 10);
    const float* gp = gnn + ((size_t)row << 10);
    float4 mv = *(const float4*)(mp + t * 4);
    float4 gv = *(const float4*)(gp + t * 4);
    ushort4 g4;
    g4.x = f2bf(gv.x); g4.y = f2bf(gv.y); g4.z = f2bf(gv.z); g4.w = f2bf(gv.w);
    *(ushort4*)(gnnbf + ((size_t)row << 10) + t * 4) = g4;
    u64 b0 = __ballot(mv.x != 0.f);
    u64 b1v = __ballot(mv.y != 0.f);
    u64 b2 = __ballot(mv.z != 0.f);
    u64 b3 = __ballot(mv.w != 0.f);
    int L = t & 63;
    if ((L & 15) == 0) {
      int m = L >> 4;
      int sh = m << 4;
      u64 W = ((b0 >> sh) & 0xFFFFull)
            | (((b1v >> sh) & 0xFFFFull) << 16)
            | (((b2 >> sh) & 0xFFFFull) << 32)
            | (((b3 >> sh) & 0xFFFFull) << 48);
      int kt = ((t >> 6) << 2) + m;
      mb[(((size_t)(b * 16 + kt)) << 10) + q] = W;
    }
  }
}

// --- LayerNorm bf16-in -> bf16 ----------------------------------------------
__global__ void __launch_bounds__(256) ln_kernel_b(
    const u16* __restrict__ x, const float* __restrict__ g,
    const float* __restrict__ bt, u16* __restrict__ out) {
  int row = blockIdx.x, t = threadIdx.x;
  const u16* xr = x + ((size_t)row << 10);
  ushort4 xv4 = *(const ushort4*)(xr + t * 4);
  float v0 = bf2f(xv4.x), v1 = bf2f(xv4.y), v2 = bf2f(xv4.z), v3 = bf2f(xv4.w);
  float s = v0 + v1 + v2 + v3;
  float q = v0 * v0 + v1 * v1 + v2 * v2 + v3 * v3;
#pragma unroll
  for (int off = 1; off < 64; off <<= 1) {
    s += __shfl_xor(s, off);
    q += __shfl_xor(q, off);
  }
  __shared__ float sb[4], qb[4];
  int w = t >> 6, l = t & 63;
  if (l == 0) { sb[w] = s; qb[w] = q; }
  __syncthreads();
  s = sb[0] + sb[1] + sb[2] + sb[3];
  q = qb[0] + qb[1] + qb[2] + qb[3];
  float mean = s * (1.f / 1024.f);
  float var = q * (1.f / 1024.f) - mean * mean;
  float rs = rsqrtf(var + 1e-5f);
  float4 gv = *(const float4*)(g + t * 4);
  float4 bv = *(const float4*)(bt + t * 4);
  ushort4 o;
  o.x = f2bf((v0 - mean) * rs * gv.x + bv.x);
  o.y = f2bf((v1 - mean) * rs * gv.y + bv.y);
  o.z = f2bf((v2 - mean) * rs * gv.z + bv.z);
  o.w = f2bf((v3 - mean) * rs * gv.w + bv.w);
  *(ushort4*)(out + ((size_t)row << 10) + t * 4) = o;
}

// ---------------------------------------------------------------------------
// Double-buffered GEMM core 64x128, BK=64, compile-time strides. 48 KiB LDS.
// Advancing stage pointers + unroll-2 K-loop: all addresses loop-invariant.
// ---------------------------------------------------------------------------
template <int LDA, int LDB, int NKT>
__device__ __forceinline__ void gemm_core_db64(
    const u16* __restrict__ A, const u16* __restrict__ Bt,
    int bm, int bn, u16* lds, f32x4 acc[4][2]) {
  const int tid = threadIdx.x;
  const int w = tid >> 6, l = tid & 63;
  const int wn = w << 5;
  const int lrow = l >> 3;
  const int cg = (l & 7) ^ lrow;
  const u16* Ab = A + (size_t)(bm << 6) * LDA + (cg << 3);
  const u16* Bb = Bt + (size_t)(bn << 7) * LDB + (cg << 3);
  const u16* pA0 = Ab + (size_t)((((w << 1) + 0) << 3) + lrow) * LDA;
  const u16* pA1 = Ab + (size_t)((((w << 1) + 1) << 3) + lrow) * LDA;
  const u16* pB0 = Bb + (size_t)((((w << 2) + 0) << 3) + lrow) * LDB;
  const u16* pB1 = Bb + (size_t)((((w << 2) + 1) << 3) + lrow) * LDB;
  const u16* pB2 = Bb + (size_t)((((w << 2) + 2) << 3) + lrow) * LDB;
  const u16* pB3 = Bb + (size_t)((((w << 2) + 3) << 3) + lrow) * LDB;
#define GSTAGE64P(BUF)                                                       \
  {                                                                          \
    u16* la = lds + (BUF) * 12288;                                           \
    u16* lb = la + 4096;                                                     \
    gld_lds16(pA0, la + (((w << 1) + 0) << 9)); pA0 += 64;                   \
    gld_lds16(pA1, la + (((w << 1) + 1) << 9)); pA1 += 64;                   \
    gld_lds16(pB0, lb + (((w << 2) + 0) << 9)); pB0 += 64;                   \
    gld_lds16(pB1, lb + (((w << 2) + 1) << 9)); pB1 += 64;                   \
    gld_lds16(pB2, lb + (((w << 2) + 2) << 9)); pB2 += 64;                   \
    gld_lds16(pB3, lb + (((w << 2) + 3) << 9)); pB3 += 64;                   \
  }
  GSTAGE64P(0);
  __syncthreads();
  const int rr = l & 15;
  const int kgb = l >> 4;
#pragma unroll 2
  for (int t = 0; t < NKT; ++t) {
    if (t + 1 < NKT) GSTAGE64P((t & 1) ^ 1);
    const u16* la = lds + (t & 1) * 12288;
    const u16* lb = la + 4096;
    bf16x8 af[2][4], bfr[2][2];
#pragma unroll
    for (int ks = 0; ks < 2; ++ks) {
      const int kg = kgb + (ks << 2);
#pragma unroll
      for (int f = 0; f < 4; ++f) {
        int ra = (f << 4) + rr;
        af[ks][f] = *(const bf16x8*)(la + (ra << 6) + ((kg ^ (ra & 7)) << 3));
      }
#pragma unroll
      for (int f = 0; f < 2; ++f) {
        int rb = wn + (f << 4) + rr;
        bfr[ks][f] = *(const bf16x8*)(lb + (rb << 6) + ((kg ^ (rb & 7)) << 3));
      }
    }
#pragma unroll
    for (int fm = 0; fm < 4; ++fm)
#pragma unroll
      for (int fn = 0; fn < 2; ++fn)
#pragma unroll
        for (int ks = 0; ks < 2; ++ks)
          acc[fm][fn] = __builtin_amdgcn_mfma_f32_16x16x32_bf16(
              af[ks][fm], bfr[ks][fn], acc[fm][fn], 0, 0, 0);
    __syncthreads();
  }
#undef GSTAGE64P
}

#define ACC_INIT64()                      \
  f32x4 acc[4][2];                        \
  { f32x4 zf = {0.f, 0.f, 0.f, 0.f};      \
_Pragma("unroll")                         \
    for (int a = 0; a < 4; ++a)           \
_Pragma("unroll")                         \
      for (int bb = 0; bb < 2; ++bb) acc[a][bb] = zf; }

#define EPI_SETUP64()                                   \
  const int w = threadIdx.x >> 6, l = threadIdx.x & 63; \
  const int wn = w << 5;

#define GEMM_LDS64()  __shared__ __attribute__((aligned(16))) u16 lds[2 * 12288]

// --- QKV: 64-row tiles; z<2 write (b,h,s,d); z==2 writes Vt directly ---------
__global__ void __launch_bounds__(256, 2) gemm_qkv(
    const u16* __restrict__ nx, const u16* __restrict__ wt,
    const float* __restrict__ bq, const float* __restrict__ bk,
    const float* __restrict__ bv, u16* __restrict__ qk, u16* __restrict__ vt) {
  GEMM_LDS64();
  ACC_INIT64();
  int z = blockIdx.z;
  const u16* Bt = wt + (size_t)z * 1024 * 1024;
  const float* bias = z == 0 ? bq : z == 1 ? bk : bv;
  const float scl = (z == 0) ? 0.18033688f : 1.0f;  // 0.125*log2(e) for Q
  gemm_core_db64<1024, 1024, 16>(nx, Bt, blockIdx.x, blockIdx.y, lds, acc);
  EPI_SETUP64();
  if (z == 2) {
    // LDS transpose: vt[b, e, s] coalesced writes (64 B runs along s)
    u16 (*tl)[72] = (u16(*)[72])lds;
#pragma unroll
    for (int fm = 0; fm < 4; ++fm)
#pragma unroll
      for (int fn = 0; fn < 2; ++fn)
#pragma unroll
        for (int j = 0; j < 4; ++j) {
          int rloc = (fm << 4) + ((l >> 4) << 2) + j;
          int cloc = wn + (fn << 4) + (l & 15);
          int col = (blockIdx.y << 7) + cloc;
          tl[cloc][rloc] = f2bf(acc[fm][fn][j] + bias[col]);
        }
    __syncthreads();
    int col = threadIdx.x >> 1, half = threadIdx.x & 1;
    int e = (blockIdx.y << 7) + col;
    int rowg = (blockIdx.x << 6) + (half << 5);
    int b = rowg >> 10, s0 = rowg & 1023;
    u16* dst = vt + ((size_t)b << 20) + ((size_t)e << 10) + s0;
    const u16* srcl = &tl[col][half << 5];
    *(uint4*)(dst)      = *(const uint4*)(srcl);
    *(uint4*)(dst + 8)  = *(const uint4*)(srcl + 8);
    *(uint4*)(dst + 16) = *(const uint4*)(srcl + 16);
    *(uint4*)(dst + 24) = *(const uint4*)(srcl + 24);
  } else {
    u16* out = qk + (size_t)z * M_ * 1024;
#pragma unroll
    for (int fm = 0; fm < 4; ++fm)
#pragma unroll
      for (int fn = 0; fn < 2; ++fn)
#pragma unroll
        for (int j = 0; j < 4; ++j) {
          int row = (blockIdx.x << 6) + (fm << 4) + ((l >> 4) << 2) + j;
          int col = (blockIdx.y << 7) + wn + (fn << 4) + (l & 15);
          float v = (acc[fm][fn][j] + bias[col]) * scl;
          int b = row >> 10, s = row & 1023;
          int h = col >> 6, d = col & 63;
          out[(((size_t)(b * 16 + h) << 10) + s) * 64 + d] = f2bf(v);
        }
  }
}

// --- gnnV: xvg[b,q,e] = gnnbf[b] @ Vt[b]^T (bf16 out), 64-row tiles ----------
__global__ void __launch_bounds__(256, 2) gemm_gnnv(
    const u16* __restrict__ gnnbf, const u16* __restrict__ vt,
    u16* __restrict__ xvg) {
  GEMM_LDS64();
  ACC_INIT64();
  int b = blockIdx.z;
  const u16* A = gnnbf + ((size_t)b << 20);
  const u16* Bt = vt + ((size_t)b << 20);
  u16* out = xvg + ((size_t)b << 20);
  gemm_core_db64<1024, 1024, 16>(A, Bt, blockIdx.x, blockIdx.y, lds, acc);
  EPI_SETUP64();
#pragma unroll
  for (int fm = 0; fm < 4; ++fm)
#pragma unroll
    for (int fn = 0; fn < 2; ++fn)
#pragma unroll
      for (int j = 0; j < 4; ++j) {
        int row = (blockIdx.x << 6) + (fm << 4) + ((l >> 4) << 2) + j;
        int col = (blockIdx.y << 7) + wn + (fn << 4) + (l & 15);
        out[((size_t)row << 10) + col] = f2bf(acc[fm][fn][j]);
      }
}

// --- Wo: x1b = bf16(x + xv@Wo + bo), 64-row tiles ----------------------------
__global__ void __launch_bounds__(256, 2) gemm_wo(
    const u16* __restrict__ xv, const u16* __restrict__ wt,
    const float* __restrict__ bo, const float* __restrict__ xres,
    u16* __restrict__ x1b) {
  GEMM_LDS64();
  ACC_INIT64();
  gemm_core_db64<1024, 1024, 16>(xv, wt, blockIdx.x, blockIdx.y, lds, acc);
  EPI_SETUP64();
#pragma unroll
  for (int fm = 0; fm < 4; ++fm)
#pragma unroll
    for (int fn = 0; fn < 2; ++fn)
#pragma unroll
      for (int j = 0; j < 4; ++j) {
        int row = (blockIdx.x << 6) + (fm << 4) + ((l >> 4) << 2) + j;
        int col = (blockIdx.y << 7) + wn + (fn << 4) + (l & 15);
        size_t idx = ((size_t)row << 10) + col;
        x1b[idx] = f2bf(acc[fm][fn][j] + bo[col] + xres[idx]);
      }
}

// --- W1: ff1 = gelu(h@W1 + bf1) bf16 (M x FF), 64-row tiles ------------------
__global__ void __launch_bounds__(256, 2) gemm_w1(
    const u16* __restrict__ hb, const u16* __restrict__ wt,
    const float* __restrict__ bf1, u16* __restrict__ ff1) {
  GEMM_LDS64();
  ACC_INIT64();
  int bid = blockIdx.x + (blockIdx.y << 6);
  int k = bid & 7, sub = bid >> 3;               // 2048 = 8 x 256, bijective
  int bx = ((k & 3) << 4) + (sub & 15);          // 0..63
  int by = ((k >> 2) << 4) + (sub >> 4);         // 0..31
  gemm_core_db64<1024, 1024, 16>(hb, wt, bx, by, lds, acc);
  EPI_SETUP64();
#pragma unroll
  for (int fm = 0; fm < 4; ++fm)
#pragma unroll
    for (int fn = 0; fn < 2; ++fn)
#pragma unroll
      for (int j = 0; j < 4; ++j) {
        int row = (bx << 6) + (fm << 4) + ((l >> 4) << 2) + j;
        int col = (by << 7) + wn + (fn << 4) + (l & 15);
        float v = acc[fm][fn][j] + bf1[col];
        float ge = 0.5f * v * (1.f + erff(v * 0.70710678118654752f));
        ff1[((size_t)row << 12) + col] = f2bf(ge);
      }
}

// --- W2: out = x1b + ff1@W2 + bf2 (fp32, K=4096), 64-row tiles ---------------
__global__ void __launch_bounds__(256, 2) gemm_w2(
    const u16* __restrict__ ff1, const u16* __restrict__ wt,
    const float* __restrict__ bf2, const u16* __restrict__ x1b,
    float* __restrict__ out) {
  GEMM_LDS64();
  ACC_INIT64();
  int bid = blockIdx.x + (blockIdx.y << 6);
  int k = bid & 7, sub = bid >> 3;               // 512 = 8 x 64, bijective
  int bx = ((k & 3) << 4) + (sub & 15);          // 0..63
  int by = ((k >> 2) << 2) + (sub >> 4);         // 0..7
  gemm_core_db64<4096, 4096, 64>(ff1, wt, bx, by, lds, acc);
  EPI_SETUP64();
#pragma unroll
  for (int fm = 0; fm < 4; ++fm)
#pragma unroll
    for (int fn = 0; fn < 2; ++fn)
#pragma unroll
      for (int j = 0; j < 4; ++j) {
        int row = (bx << 6) + (fm << 4) + ((l >> 4) << 2) + j;
        int col = (by << 7) + wn + (fn << 4) + (l & 15);
        size_t idx = ((size_t)row << 10) + col;
        out[idx] = acc[fm][fn][j] + bf2[col] + bf2f(x1b[idx]);
      }
}

// ---------------------------------------------------------------------------
// Flash attention, fixed-shift softmax (C=8, exp2 domain), bitmask C-init.
// Grid: 512 blocks (XCD-chunked); 4 waves x 32 q-rows; KV tile 64.
// ---------------------------------------------------------------------------
__global__ void __launch_bounds__(256, 2) attn_kernel(
    const u16* __restrict__ Q, const u16* __restrict__ K,
    const u16* __restrict__ Vt, const u64* __restrict__ mb,
    const u16* __restrict__ xvg, u16* __restrict__ xv) {
  const int lin = ((blockIdx.x & 7) << 6) + (blockIdx.x >> 3);  // XCD chunk
  const int qt = lin & 7, h = (lin >> 3) & 15, b = lin >> 7;
  const int tid = threadIdx.x, w = tid >> 6, l = tid & 63;
  __shared__ __attribute__((aligned(16))) u16 kbuf[2][64 * 64];
  __shared__ __attribute__((aligned(16))) u16 vbuf[2][64 * 64];
  __shared__ __attribute__((aligned(16))) u16 pbuf[4][32 * 64];
  const size_t bh = ((size_t)(b * 16 + h)) << 16;
  const u16* Qb = Q + bh;
  const u16* Kb = K + bh;
  const u16* Vtb = Vt + ((size_t)b << 20) + ((size_t)(h * 64) << 10);
  const u64* mbb = mb + (((size_t)(b * 16)) << 10);
  const int q0 = (qt << 7) + (w << 5);
  const int lrow = l >> 3, cg = (l & 7) ^ lrow;
  const int l4 = l >> 4, lo = l & 15;
  const int p0 = ((lo & 3) << 4) + (lo >> 2);
  u16* p_w = pbuf[w];
  const float FU = -8.0f, FM = -30008.0f;

  bf16x8 qf[2][2];
#pragma unroll
  for (int m = 0; m < 2; ++m)
#pragma unroll
    for (int ks = 0; ks < 2; ++ks)
      qf[m][ks] = *(const bf16x8*)(Qb + ((size_t)(q0 + m * 16 + lo) << 6) +
                                   l4 * 8 + ks * 32);
  bf16x8 onesf;
#pragma unroll
  for (int j = 0; j < 8; ++j) onesf[j] = (short)0x3F80;

  f32x4 osoft[2][4], osum[2];
  f32x4 zf = {0.f, 0.f, 0.f, 0.f};
#pragma unroll
  for (int m = 0; m < 2; ++m) {
    osum[m] = zf;
#pragma unroll
    for (int fd = 0; fd < 4; ++fd) osoft[m][fd] = zf;
  }

#define STAGE(T, BUF)                                                          \
  {                                                                            \
    int kv0s = (T) << 6;                                                       \
    u16* kd = &kbuf[BUF][0];                                                   \
    u16* vd = &vbuf[BUF][0];                                                   \
    _Pragma("unroll") for (int i = 0; i < 2; ++i) {                            \
      int c = (w << 1) + i;                                                    \
      gld_lds16(Kb + ((size_t)(kv0s + (c << 3) + lrow) << 6) + (cg << 3),      \
                kd + (c << 9));                                                \
      gld_lds16(Vtb + ((size_t)((c << 3) + lrow) << 10) + kv0s + (cg << 3),    \
                vd + (c << 9));                                                \
    }                                                                          \
  }

  STAGE(0, 0);
  __syncthreads();

  for (int t = 0; t < 16; ++t) {
    const int cur = t & 1;
    if (t < 15) STAGE(t + 1, cur ^ 1);
    const u16* kb_ = &kbuf[cur][0];
    const u16* vb_ = &vbuf[cur][0];
    const u64* mbt = mbb + (((size_t)t) << 10);
    // C-init from bitmask (exp2 domain: -8 unmasked / -30008 masked)
    f32x4 sacc[2][4];
#pragma unroll
    for (int m = 0; m < 2; ++m)
#pragma unroll
      for (int j = 0; j < 4; ++j) {
        u64 wb = mbt[q0 + (m << 4) + (l4 << 2) + j];
        unsigned int bits = (unsigned int)(wb >> p0);
        sacc[m][0][j] = (bits & 1u) ? FU : FM;
        sacc[m][1][j] = (bits & 16u) ? FU : FM;
        sacc[m][2][j] = (bits & 256u) ? FU : FM;
        sacc[m][3][j] = (bits & 4096u) ? FU : FM;
      }
    // QK^T
    __builtin_amdgcn_s_setprio(1);
#pragma unroll
    for (int ks = 0; ks < 2; ++ks) {
      const int kg = l4 + (ks << 2);
      bf16x8 kf[4];
#pragma unroll
      for (int fn = 0; fn < 4; ++fn) {
        int rk = (fn << 4) + lo;
        kf[fn] = *(const bf16x8*)(kb_ + (rk << 6) + ((kg ^ (rk & 7)) << 3));
      }
#pragma unroll
      for (int m = 0; m < 2; ++m)
#pragma unroll
        for (int fn = 0; fn < 4; ++fn)
          sacc[m][fn] = __builtin_amdgcn_mfma_f32_16x16x32_bf16(
              qf[m][ks], kf[fn], sacc[m][fn], 0, 0, 0);
    }
    __builtin_amdgcn_s_setprio(0);
    // P = exp2(s), pack to bf16, store to per-wave LDS
#pragma unroll
    for (int m = 0; m < 2; ++m)
#pragma unroll
      for (int fn = 0; fn < 4; ++fn)
#pragma unroll
        for (int j = 0; j < 4; ++j) {
          float p = exp2f(sacc[m][fn][j]);
          unsigned int u = __builtin_bit_cast(unsigned int, p);
          int prow = (m << 4) + (l4 << 2) + j;
          int pcol = (fn << 4) + lo;
          p_w[(prow << 6) + (pcol ^ ((prow & 7) << 3))] =
              (u16)((u + 0x8000u) >> 16);
        }
    // PV + ones-column rowsum
    __builtin_amdgcn_s_setprio(1);
#pragma unroll
    for (int ks = 0; ks < 2; ++ks) {
      const int kg = l4 + (ks << 2);
      bf16x8 pf[2], vf[4];
#pragma unroll
      for (int m = 0; m < 2; ++m) {
        int pr = (m << 4) + lo;
        pf[m] = *(const bf16x8*)(p_w + (pr << 6) + ((kg ^ (pr & 7)) << 3));
      }
#pragma unroll
      for (int fd = 0; fd < 4; ++fd) {
        int rd = (fd << 4) + lo;
        vf[fd] = *(const bf16x8*)(vb_ + (rd << 6) + ((kg ^ (rd & 7)) << 3));
      }
#pragma unroll
      for (int m = 0; m < 2; ++m) {
        osum[m] = __builtin_amdgcn_mfma_f32_16x16x32_bf16(
            pf[m], onesf, osum[m], 0, 0, 0);
#pragma unroll
        for (int fd = 0; fd < 4; ++fd)
          osoft[m][fd] = __builtin_amdgcn_mfma_f32_16x16x32_bf16(
              pf[m], vf[fd], osoft[m][fd], 0, 0, 0);
      }
    }
    __builtin_amdgcn_s_setprio(0);
    __syncthreads();
  }
  // epilogue
#pragma unroll
  for (int m = 0; m < 2; ++m) {
    f32x4 rl;
#pragma unroll
    for (int j = 0; j < 4; ++j) rl[j] = 1.0f / osum[m][j];
#pragma unroll
    for (int fd = 0; fd < 4; ++fd)
#pragma unroll
      for (int j = 0; j < 4; ++j) {
        int qrow = q0 + (m << 4) + (l4 << 2) + j;
        int e = (h << 6) + (fd << 4) + lo;
        size_t idx = (((size_t)(b * 1024 + qrow)) << 10) + e;
        float o = osoft[m][fd][j] * rl[j] + bf2f(xvg[idx]);
        xv[idx] = f2bf(o);
      }
  }
#undef STAGE
}

// ---------------------------------------------------------------------------
extern "C" void kernel_launch(void* const* d_in, const int* in_sizes, int n_in,
                              void* d_out, int out_size, void* d_ws, size_t ws_size,
                              hipStream_t stream) {
  (void)in_sizes; (void)n_in; (void)out_size; (void)ws_size;
  const float* x   = (const float*)d_in[0];
  const float* mask= (const float*)d_in[1];
  const float* gnn = (const float*)d_in[2];
  const float* Wq  = (const float*)d_in[3];
  const float* bq  = (const float*)d_in[4];
  const float* Wk  = (const float*)d_in[5];
  const float* bk  = (const float*)d_in[6];
  const float* Wv  = (const float*)d_in[7];
  const float* bv  = (const float*)d_in[8];
  const float* Wo  = (const float*)d_in[9];
  const float* bo  = (const float*)d_in[10];
  const float* g1  = (const float*)d_in[11];
  const float* b1  = (const float*)d_in[12];
  const float* g2  = (const float*)d_in[13];
  const float* b2  = (const float*)d_in[14];
  const float* W1  = (const float*)d_in[15];
  const float* bf1 = (const float*)d_in[16];
  const float* W2  = (const float*)d_in[17];
  const float* bf2 = (const float*)d_in[18];
  float* out = (float*)d_out;

  char* ws = (char*)d_ws;
  const size_t MB = 1024 * 1024;
  // layout (MB): 0-24 wt | 24-32 nx -> xvbuf -> hbuf | 32-40 Q | 40-48 K
  // | 48-56 Vt | 56-57 mb (bitmask) | 64-72 gnnbf -> x1b | 72-80 xvg
  // post-attn: ff1 32-64
  u16*  wt    = (u16*)(ws);
  u16*  nx    = (u16*)(ws + 24 * MB);
  u16*  xvbuf = (u16*)(ws + 24 * MB);
  u16*  hbuf  = (u16*)(ws + 24 * MB);
  u16*  qk    = (u16*)(ws + 32 * MB);
  u16*  vt    = (u16*)(ws + 48 * MB);
  u64*  mb    = (u64*)(ws + 56 * MB);
  u16*  gnnbf = (u16*)(ws + 64 * MB);
  u16*  x1b   = (u16*)(ws + 64 * MB);
  u16*  xvg   = (u16*)(ws + 72 * MB);
  u16*  ff1   = (u16*)(ws + 32 * MB);

  pre_kernel<<<20480, 256, 0, stream>>>(Wq, Wk, Wv, Wo, W1, W2, wt,
                                        x, g1, b1, nx, mask, gnn, mb, gnnbf);
  gemm_qkv<<<dim3(64, 8, 3), 256, 0, stream>>>(nx, wt, bq, bk, bv, qk, vt);
  gemm_gnnv<<<dim3(16, 8, 4), 256, 0, stream>>>(gnnbf, vt, xvg);
  attn_kernel<<<512, 256, 0, stream>>>(
      qk, qk + (size_t)4 * MB, vt, mb, xvg, xvbuf);
  gemm_wo<<<dim3(64, 8), 256, 0, stream>>>(xvbuf, wt + (size_t)3 * MB, bo, x, x1b);
  ln_kernel_b<<<4096, 256, 0, stream>>>(x1b, g2, b2, hbuf);
  gemm_w1<<<dim3(64, 32), 256, 0, stream>>>(hbuf, wt + (size_t)4 * MB, bf1, ff1);
  gemm_w2<<<dim3(64, 8), 256, 0, stream>>>(ff1, wt + (size_t)8 * MB, bf2, x1b, out);
}

// Round 15
// 226.276 us; speedup vs baseline: 1.0091x; 1.0091x over previous
//
#include <hip/hip_runtime.h>
#include <hip/hip_bf16.h>

typedef unsigned short u16;
typedef short bf16x8 __attribute__((ext_vector_type(8)));
typedef float f32x4 __attribute__((ext_vector_type(4)));
typedef unsigned long long u64;

#define B_ 4
#define S_ 1024
#define E_ 1024
#define H_ 16
#define FF_ 4096
#define D_ 64
#define M_ 4096  /* B*S */

__device__ __forceinline__ u16 f2bf(float f) {
  unsigned int u = __builtin_bit_cast(unsigned int, f);
  u += 0x7fffu + ((u >> 16) & 1u);   // RNE
  return (u16)(u >> 16);
}
__device__ __forceinline__ float bf2f(u16 v) {
  unsigned int u = ((unsigned int)v) << 16;
  return __builtin_bit_cast(float, u);
}

__device__ __forceinline__ void gld_lds16(const void* g, void* l) {
  __builtin_amdgcn_global_load_lds((__attribute__((address_space(1))) void*)g,
                                   (__attribute__((address_space(3))) void*)l,
                                   16, 0, 0);
}

// ---------------------------------------------------------------------------
// Fused prologue: [0,12288) weight cast+transpose; [12288,16384) LN1;
// [16384,20480) mask->bitmask + gnn->bf16.
// ---------------------------------------------------------------------------
__global__ void __launch_bounds__(256) pre_kernel(
    const float* __restrict__ wq, const float* __restrict__ wk,
    const float* __restrict__ wv, const float* __restrict__ wo,
    const float* __restrict__ w1, const float* __restrict__ w2,
    u16* __restrict__ wt,
    const float* __restrict__ x, const float* __restrict__ g1,
    const float* __restrict__ b1, u16* __restrict__ nx,
    const float* __restrict__ mask, const float* __restrict__ gnn,
    u64* __restrict__ mb, u16* __restrict__ gnnbf) {
  __shared__ __attribute__((aligned(16))) float smem_f[1088];
  int bid = blockIdx.x;
  int t = threadIdx.x;
  if (bid < 12288) {
    const float* src; u16* dst; int K, N; int local;
    if (bid < 4096) {
      int wsel = bid >> 10; local = bid & 1023; K = 1024; N = 1024;
      src = wsel == 0 ? wq : wsel == 1 ? wk : wsel == 2 ? wv : wo;
      dst = wt + (size_t)wsel * 1024 * 1024;
    } else if (bid < 8192) {
      local = bid - 4096; K = 1024; N = 4096; src = w1;
      dst = wt + (size_t)4 * 1024 * 1024;
    } else {
      local = bid - 8192; K = 4096; N = 1024; src = w2;
      dst = wt + (size_t)8 * 1024 * 1024;
    }
    int tiles_n = N >> 5;
    int n0 = (local % tiles_n) << 5, k0 = (local / tiles_n) << 5;
    float (*tl)[33] = reinterpret_cast<float(*)[33]>(smem_f);
    int tx = t & 31, ty = t >> 5;
#pragma unroll
    for (int i = 0; i < 4; ++i)
      tl[ty + i * 8][tx] = src[(size_t)(k0 + ty + i * 8) * N + n0 + tx];
    __syncthreads();
#pragma unroll
    for (int i = 0; i < 4; ++i)
      dst[(size_t)(n0 + ty + i * 8) * K + k0 + tx] = f2bf(tl[tx][ty + i * 8]);
  } else if (bid < 16384) {
    int row = bid - 12288;
    const float* xr = x + (size_t)row * 1024;
    float4 v = *(const float4*)(xr + t * 4);
    float s = v.x + v.y + v.z + v.w;
    float q = v.x * v.x + v.y * v.y + v.z * v.z + v.w * v.w;
#pragma unroll
    for (int off = 1; off < 64; off <<= 1) {
      s += __shfl_xor(s, off);
      q += __shfl_xor(q, off);
    }
    float* sb = smem_f;
    float* qb = smem_f + 4;
    int w = t >> 6, l = t & 63;
    if (l == 0) { sb[w] = s; qb[w] = q; }
    __syncthreads();
    s = sb[0] + sb[1] + sb[2] + sb[3];
    q = qb[0] + qb[1] + qb[2] + qb[3];
    float mean = s * (1.f / 1024.f);
    float var = q * (1.f / 1024.f) - mean * mean;
    float rs = rsqrtf(var + 1e-5f);
    float4 gv = *(const float4*)(g1 + t * 4);
    float4 bv = *(const float4*)(b1 + t * 4);
    ushort4 o;
    o.x = f2bf((v.x - mean) * rs * gv.x + bv.x);
    o.y = f2bf((v.y - mean) * rs * gv.y + bv.y);
    o.z = f2bf((v.z - mean) * rs * gv.z + bv.z);
    o.w = f2bf((v.w - mean) * rs * gv.w + bv.w);
    *(ushort4*)(nx + (size_t)row * 1024 + t * 4) = o;
  } else {
    int row = bid - 16384;
    int b = row >> 10, q = row & 1023;
    const float* mp = mask + ((size_t)row << 10);
    const float* gp = gnn + ((size_t)row << 10);
    float4 mv = *(const float4*)(mp + t * 4);
    float4 gv = *(const float4*)(gp + t * 4);
    ushort4 g4;
    g4.x = f2bf(gv.x); g4.y = f2bf(gv.y); g4.z = f2bf(gv.z); g4.w = f2bf(gv.w);
    *(ushort4*)(gnnbf + ((size_t)row << 10) + t * 4) = g4;
    u64 b0 = __ballot(mv.x != 0.f);
    u64 b1v = __ballot(mv.y != 0.f);
    u64 b2 = __ballot(mv.z != 0.f);
    u64 b3 = __ballot(mv.w != 0.f);
    int L = t & 63;
    if ((L & 15) == 0) {
      int m = L >> 4;
      int sh = m << 4;
      u64 W = ((b0 >> sh) & 0xFFFFull)
            | (((b1v >> sh) & 0xFFFFull) << 16)
            | (((b2 >> sh) & 0xFFFFull) << 32)
            | (((b3 >> sh) & 0xFFFFull) << 48);
      int kt = ((t >> 6) << 2) + m;
      mb[(((size_t)(b * 16 + kt)) << 10) + q] = W;
    }
  }
}

// --- LayerNorm bf16-in -> bf16 ----------------------------------------------
__global__ void __launch_bounds__(256) ln_kernel_b(
    const u16* __restrict__ x, const float* __restrict__ g,
    const float* __restrict__ bt, u16* __restrict__ out) {
  int row = blockIdx.x, t = threadIdx.x;
  const u16* xr = x + ((size_t)row << 10);
  ushort4 xv4 = *(const ushort4*)(xr + t * 4);
  float v0 = bf2f(xv4.x), v1 = bf2f(xv4.y), v2 = bf2f(xv4.z), v3 = bf2f(xv4.w);
  float s = v0 + v1 + v2 + v3;
  float q = v0 * v0 + v1 * v1 + v2 * v2 + v3 * v3;
#pragma unroll
  for (int off = 1; off < 64; off <<= 1) {
    s += __shfl_xor(s, off);
    q += __shfl_xor(q, off);
  }
  __shared__ float sb[4], qb[4];
  int w = t >> 6, l = t & 63;
  if (l == 0) { sb[w] = s; qb[w] = q; }
  __syncthreads();
  s = sb[0] + sb[1] + sb[2] + sb[3];
  q = qb[0] + qb[1] + qb[2] + qb[3];
  float mean = s * (1.f / 1024.f);
  float var = q * (1.f / 1024.f) - mean * mean;
  float rs = rsqrtf(var + 1e-5f);
  float4 gv = *(const float4*)(g + t * 4);
  float4 bv = *(const float4*)(bt + t * 4);
  ushort4 o;
  o.x = f2bf((v0 - mean) * rs * gv.x + bv.x);
  o.y = f2bf((v1 - mean) * rs * gv.y + bv.y);
  o.z = f2bf((v2 - mean) * rs * gv.z + bv.z);
  o.w = f2bf((v3 - mean) * rs * gv.w + bv.w);
  *(ushort4*)(out + ((size_t)row << 10) + t * 4) = o;
}

// ---------------------------------------------------------------------------
// Double-buffered GEMM core 64x128, BK=64, compile-time strides. 48 KiB LDS.
// ---------------------------------------------------------------------------
template <int LDA, int LDB, int NKT>
__device__ __forceinline__ void gemm_core_db64(
    const u16* __restrict__ A, const u16* __restrict__ Bt,
    int bm, int bn, u16* lds, f32x4 acc[4][2]) {
  const int tid = threadIdx.x;
  const int w = tid >> 6, l = tid & 63;
  const int wn = w << 5;
  const int lrow = l >> 3;
  const int cg = (l & 7) ^ lrow;
  const u16* Ab = A + (size_t)(bm << 6) * LDA + (cg << 3);
  const u16* Bb = Bt + (size_t)(bn << 7) * LDB + (cg << 3);
#define GSTAGE64(T, BUF)                                                     \
  {                                                                          \
    const int kk = (T) << 6;                                                 \
    u16* la = lds + (BUF) * 12288;                                           \
    u16* lb = la + 4096;                                                     \
    _Pragma("unroll") for (int i = 0; i < 2; ++i) {                          \
      int c = (w << 1) + i;                                                  \
      int row = (c << 3) + lrow;                                             \
      gld_lds16(Ab + (size_t)row * LDA + kk, la + (c << 9));                 \
    }                                                                        \
    _Pragma("unroll") for (int i = 0; i < 4; ++i) {                          \
      int c = (w << 2) + i;                                                  \
      int row = (c << 3) + lrow;                                             \
      gld_lds16(Bb + (size_t)row * LDB + kk, lb + (c << 9));                 \
    }                                                                        \
  }
  GSTAGE64(0, 0);
  __syncthreads();
  for (int t = 0; t < NKT; ++t) {
    if (t + 1 < NKT) GSTAGE64(t + 1, (t & 1) ^ 1);
    const u16* la = lds + (t & 1) * 12288;
    const u16* lb = la + 4096;
    bf16x8 af[2][4], bfr[2][2];
    const int rr = l & 15;
    const int kgb = l >> 4;
#pragma unroll
    for (int ks = 0; ks < 2; ++ks) {
      const int kg = kgb + (ks << 2);
#pragma unroll
      for (int f = 0; f < 4; ++f) {
        int ra = (f << 4) + rr;
        af[ks][f] = *(const bf16x8*)(la + (ra << 6) + ((kg ^ (ra & 7)) << 3));
      }
#pragma unroll
      for (int f = 0; f < 2; ++f) {
        int rb = wn + (f << 4) + rr;
        bfr[ks][f] = *(const bf16x8*)(lb + (rb << 6) + ((kg ^ (rb & 7)) << 3));
      }
    }
#pragma unroll
    for (int fm = 0; fm < 4; ++fm)
#pragma unroll
      for (int fn = 0; fn < 2; ++fn)
#pragma unroll
        for (int ks = 0; ks < 2; ++ks)
          acc[fm][fn] = __builtin_amdgcn_mfma_f32_16x16x32_bf16(
              af[ks][fm], bfr[ks][fn], acc[fm][fn], 0, 0, 0);
    __syncthreads();
  }
#undef GSTAGE64
}

// ---------------------------------------------------------------------------
// 3-deep pipelined GEMM core 64x128, BK=64, counted vmcnt + raw barriers.
// ---------------------------------------------------------------------------
template <int LDA, int LDB, int NKT>
__device__ __forceinline__ void gemm_core_p3(
    const u16* __restrict__ A, const u16* __restrict__ Bt,
    int bm, int bn, u16* lds, f32x4 acc[4][2]) {
  const int tid = threadIdx.x;
  const int w = tid >> 6, l = tid & 63;
  const int wn = w << 5;
  const int lrow = l >> 3;
  const int cg = (l & 7) ^ lrow;
  const u16* Ab = A + (size_t)(bm << 6) * LDA + (cg << 3);
  const u16* Bb = Bt + (size_t)(bn << 7) * LDB + (cg << 3);
#define PSTAGE(T, BUF)                                                       \
  {                                                                          \
    const int kk = (T) << 6;                                                 \
    u16* la = lds + (BUF) * 12288;                                           \
    u16* lb = la + 4096;                                                     \
    _Pragma("unroll") for (int i = 0; i < 2; ++i) {                          \
      int c = (w << 1) + i;                                                  \
      int row = (c << 3) + lrow;                                             \
      gld_lds16(Ab + (size_t)row * LDA + kk, la + (c << 9));                 \
    }                                                                        \
    _Pragma("unroll") for (int i = 0; i < 4; ++i) {                          \
      int c = (w << 2) + i;                                                  \
      int row = (c << 3) + lrow;                                             \
      gld_lds16(Bb + (size_t)row * LDB + kk, lb + (c << 9));                 \
    }                                                                        \
  }
  PSTAGE(0, 0);
  PSTAGE(1, 1);
  int cur = 0;
  for (int t = 0; t < NKT; ++t) {
    if (t + 2 < NKT) {
      int nb = cur + 2; if (nb >= 3) nb -= 3;
      PSTAGE(t + 2, nb);
      asm volatile("s_waitcnt vmcnt(12)" ::: "memory");
    } else if (t + 1 < NKT) {
      asm volatile("s_waitcnt vmcnt(6)" ::: "memory");
    } else {
      asm volatile("s_waitcnt vmcnt(0)" ::: "memory");
    }
    __builtin_amdgcn_sched_barrier(0);
    __builtin_amdgcn_s_barrier();
    const u16* la = lds + cur * 12288;
    const u16* lb = la + 4096;
    bf16x8 af[2][4], bfr[2][2];
    const int rr = l & 15;
    const int kgb = l >> 4;
#pragma unroll
    for (int ks = 0; ks < 2; ++ks) {
      const int kg = kgb + (ks << 2);
#pragma unroll
      for (int f = 0; f < 4; ++f) {
        int ra = (f << 4) + rr;
        af[ks][f] = *(const bf16x8*)(la + (ra << 6) + ((kg ^ (ra & 7)) << 3));
      }
#pragma unroll
      for (int f = 0; f < 2; ++f) {
        int rb = wn + (f << 4) + rr;
        bfr[ks][f] = *(const bf16x8*)(lb + (rb << 6) + ((kg ^ (rb & 7)) << 3));
      }
    }
    __builtin_amdgcn_s_setprio(1);
#pragma unroll
    for (int fm = 0; fm < 4; ++fm)
#pragma unroll
      for (int fn = 0; fn < 2; ++fn)
#pragma unroll
        for (int ks = 0; ks < 2; ++ks)
          acc[fm][fn] = __builtin_amdgcn_mfma_f32_16x16x32_bf16(
              af[ks][fm], bfr[ks][fn], acc[fm][fn], 0, 0, 0);
    __builtin_amdgcn_s_setprio(0);
    asm volatile("s_waitcnt lgkmcnt(0)" ::: "memory");
    __builtin_amdgcn_sched_barrier(0);
    __builtin_amdgcn_s_barrier();
    cur = (cur == 2) ? 0 : cur + 1;
  }
#undef PSTAGE
}

#define ACC_INIT64()                      \
  f32x4 acc[4][2];                        \
  { f32x4 zf = {0.f, 0.f, 0.f, 0.f};      \
_Pragma("unroll")                         \
    for (int a = 0; a < 4; ++a)           \
_Pragma("unroll")                         \
      for (int bb = 0; bb < 2; ++bb) acc[a][bb] = zf; }

#define EPI_SETUP64()                                   \
  const int w = threadIdx.x >> 6, l = threadIdx.x & 63; \
  const int wn = w << 5;

#define GEMM_LDS64()  __shared__ __attribute__((aligned(16))) u16 lds[2 * 12288]

// --- QKV: 64-row tiles; z<2 write (b,h,s,d); z==2 writes Vt directly ---------
__global__ void __launch_bounds__(256, 2) gemm_qkv(
    const u16* __restrict__ nx, const u16* __restrict__ wt,
    const float* __restrict__ bq, const float* __restrict__ bk,
    const float* __restrict__ bv, u16* __restrict__ qk, u16* __restrict__ vt) {
  GEMM_LDS64();
  ACC_INIT64();
  int z = blockIdx.z;
  const u16* Bt = wt + (size_t)z * 1024 * 1024;
  const float* bias = z == 0 ? bq : z == 1 ? bk : bv;
  const float scl = (z == 0) ? 0.18033688f : 1.0f;  // 0.125*log2(e) for Q
  gemm_core_db64<1024, 1024, 16>(nx, Bt, blockIdx.x, blockIdx.y, lds, acc);
  EPI_SETUP64();
  if (z == 2) {
    // LDS transpose: vt[b, e, s] coalesced writes (64 B runs along s)
    u16 (*tl)[72] = (u16(*)[72])lds;
#pragma unroll
    for (int fm = 0; fm < 4; ++fm)
#pragma unroll
      for (int fn = 0; fn < 2; ++fn)
#pragma unroll
        for (int j = 0; j < 4; ++j) {
          int rloc = (fm << 4) + ((l >> 4) << 2) + j;
          int cloc = wn + (fn << 4) + (l & 15);
          int col = (blockIdx.y << 7) + cloc;
          tl[cloc][rloc] = f2bf(acc[fm][fn][j] + bias[col]);
        }
    __syncthreads();
    int col = threadIdx.x >> 1, half = threadIdx.x & 1;
    int e = (blockIdx.y << 7) + col;
    int rowg = (blockIdx.x << 6) + (half << 5);
    int b = rowg >> 10, s0 = rowg & 1023;
    u16* dst = vt + ((size_t)b << 20) + ((size_t)e << 10) + s0;
    const u16* srcl = &tl[col][half << 5];
    *(uint4*)(dst)      = *(const uint4*)(srcl);
    *(uint4*)(dst + 8)  = *(const uint4*)(srcl + 8);
    *(uint4*)(dst + 16) = *(const uint4*)(srcl + 16);
    *(uint4*)(dst + 24) = *(const uint4*)(srcl + 24);
  } else {
    u16* out = qk + (size_t)z * M_ * 1024;
#pragma unroll
    for (int fm = 0; fm < 4; ++fm)
#pragma unroll
      for (int fn = 0; fn < 2; ++fn)
#pragma unroll
        for (int j = 0; j < 4; ++j) {
          int row = (blockIdx.x << 6) + (fm << 4) + ((l >> 4) << 2) + j;
          int col = (blockIdx.y << 7) + wn + (fn << 4) + (l & 15);
          float v = (acc[fm][fn][j] + bias[col]) * scl;
          int b = row >> 10, s = row & 1023;
          int h = col >> 6, d = col & 63;
          out[(((size_t)(b * 16 + h) << 10) + s) * 64 + d] = f2bf(v);
        }
  }
}

// --- gnnV: xvg[b,q,e] = gnnbf[b] @ Vt[b]^T (bf16 out), 64-row tiles ----------
__global__ void __launch_bounds__(256, 2) gemm_gnnv(
    const u16* __restrict__ gnnbf, const u16* __restrict__ vt,
    u16* __restrict__ xvg) {
  GEMM_LDS64();
  ACC_INIT64();
  int b = blockIdx.z;
  const u16* A = gnnbf + ((size_t)b << 20);
  const u16* Bt = vt + ((size_t)b << 20);
  u16* out = xvg + ((size_t)b << 20);
  gemm_core_db64<1024, 1024, 16>(A, Bt, blockIdx.x, blockIdx.y, lds, acc);
  EPI_SETUP64();
#pragma unroll
  for (int fm = 0; fm < 4; ++fm)
#pragma unroll
    for (int fn = 0; fn < 2; ++fn)
#pragma unroll
      for (int j = 0; j < 4; ++j) {
        int row = (blockIdx.x << 6) + (fm << 4) + ((l >> 4) << 2) + j;
        int col = (blockIdx.y << 7) + wn + (fn << 4) + (l & 15);
        out[((size_t)row << 10) + col] = f2bf(acc[fm][fn][j]);
      }
}

// --- Wo: x1b = bf16(x + xv@Wo + bo), 64-row tiles ----------------------------
__global__ void __launch_bounds__(256, 2) gemm_wo(
    const u16* __restrict__ xv, const u16* __restrict__ wt,
    const float* __restrict__ bo, const float* __restrict__ xres,
    u16* __restrict__ x1b) {
  GEMM_LDS64();
  ACC_INIT64();
  gemm_core_db64<1024, 1024, 16>(xv, wt, blockIdx.x, blockIdx.y, lds, acc);
  EPI_SETUP64();
#pragma unroll
  for (int fm = 0; fm < 4; ++fm)
#pragma unroll
    for (int fn = 0; fn < 2; ++fn)
#pragma unroll
      for (int j = 0; j < 4; ++j) {
        int row = (blockIdx.x << 6) + (fm << 4) + ((l >> 4) << 2) + j;
        int col = (blockIdx.y << 7) + wn + (fn << 4) + (l & 15);
        size_t idx = ((size_t)row << 10) + col;
        x1b[idx] = f2bf(acc[fm][fn][j] + bo[col] + xres[idx]);
      }
}

// --- W1: ff1 = gelu(h@W1 + bf1) bf16 (M x FF), 64-row tiles (best: 58us) -----
__global__ void __launch_bounds__(256, 2) gemm_w1(
    const u16* __restrict__ hb, const u16* __restrict__ wt,
    const float* __restrict__ bf1, u16* __restrict__ ff1) {
  GEMM_LDS64();
  ACC_INIT64();
  gemm_core_db64<1024, 1024, 16>(hb, wt, blockIdx.x, blockIdx.y, lds, acc);
  EPI_SETUP64();
#pragma unroll
  for (int fm = 0; fm < 4; ++fm)
#pragma unroll
    for (int fn = 0; fn < 2; ++fn)
#pragma unroll
      for (int j = 0; j < 4; ++j) {
        int row = (blockIdx.x << 6) + (fm << 4) + ((l >> 4) << 2) + j;
        int col = (blockIdx.y << 7) + wn + (fn << 4) + (l & 15);
        float v = acc[fm][fn][j] + bf1[col];
        float ge = 0.5f * v * (1.f + erff(v * 0.70710678118654752f));
        ff1[((size_t)row << 12) + col] = f2bf(ge);
      }
}

// --- W2: out = x1b + ff1@W2 + bf2 (fp32, K=4096), 64-row tiles, p3 core ------
__global__ void __launch_bounds__(256, 2) gemm_w2(
    const u16* __restrict__ ff1, const u16* __restrict__ wt,
    const float* __restrict__ bf2, const u16* __restrict__ x1b,
    float* __restrict__ out) {
  extern __shared__ __attribute__((aligned(16))) u16 lds[];
  ACC_INIT64();
  gemm_core_p3<4096, 4096, 64>(ff1, wt, blockIdx.x, blockIdx.y, lds, acc);
  EPI_SETUP64();
#pragma unroll
  for (int fm = 0; fm < 4; ++fm)
#pragma unroll
    for (int fn = 0; fn < 2; ++fn)
#pragma unroll
      for (int j = 0; j < 4; ++j) {
        int row = (blockIdx.x << 6) + (fm << 4) + ((l >> 4) << 2) + j;
        int col = (blockIdx.y << 7) + wn + (fn << 4) + (l & 15);
        size_t idx = ((size_t)row << 10) + col;
        out[idx] = acc[fm][fn][j] + bf2[col] + bf2f(x1b[idx]);
      }
}

// ---------------------------------------------------------------------------
// Flash attention, fixed-shift softmax (C=8, exp2 domain), bitmask C-init.
// Grid: 512 blocks (XCD-chunked); 4 waves x 32 q-rows; KV tile 64.
// ---------------------------------------------------------------------------
__global__ void __launch_bounds__(256, 2) attn_kernel(
    const u16* __restrict__ Q, const u16* __restrict__ K,
    const u16* __restrict__ Vt, const u64* __restrict__ mb,
    const u16* __restrict__ xvg, u16* __restrict__ xv) {
  const int lin = ((blockIdx.x & 7) << 6) + (blockIdx.x >> 3);  // XCD chunk
  const int qt = lin & 7, h = (lin >> 3) & 15, b = lin >> 7;
  const int tid = threadIdx.x, w = tid >> 6, l = tid & 63;
  __shared__ __attribute__((aligned(16))) u16 kbuf[2][64 * 64];
  __shared__ __attribute__((aligned(16))) u16 vbuf[2][64 * 64];
  __shared__ __attribute__((aligned(16))) u16 pbuf[4][32 * 64];
  const size_t bh = ((size_t)(b * 16 + h)) << 16;
  const u16* Qb = Q + bh;
  const u16* Kb = K + bh;
  const u16* Vtb = Vt + ((size_t)b << 20) + ((size_t)(h * 64) << 10);
  const u64* mbb = mb + (((size_t)(b * 16)) << 10);
  const int q0 = (qt << 7) + (w << 5);
  const int lrow = l >> 3, cg = (l & 7) ^ lrow;
  const int l4 = l >> 4, lo = l & 15;
  const int p0 = ((lo & 3) << 4) + (lo >> 2);
  u16* p_w = pbuf[w];
  const float FU = -8.0f, FM = -30008.0f;

  bf16x8 qf[2][2];
#pragma unroll
  for (int m = 0; m < 2; ++m)
#pragma unroll
    for (int ks = 0; ks < 2; ++ks)
      qf[m][ks] = *(const bf16x8*)(Qb + ((size_t)(q0 + m * 16 + lo) << 6) +
                                   l4 * 8 + ks * 32);
  bf16x8 onesf;
#pragma unroll
  for (int j = 0; j < 8; ++j) onesf[j] = (short)0x3F80;

  f32x4 osoft[2][4], osum[2];
  f32x4 zf = {0.f, 0.f, 0.f, 0.f};
#pragma unroll
  for (int m = 0; m < 2; ++m) {
    osum[m] = zf;
#pragma unroll
    for (int fd = 0; fd < 4; ++fd) osoft[m][fd] = zf;
  }

#define STAGE(T, BUF)                                                          \
  {                                                                            \
    int kv0s = (T) << 6;                                                       \
    u16* kd = &kbuf[BUF][0];                                                   \
    u16* vd = &vbuf[BUF][0];                                                   \
    _Pragma("unroll") for (int i = 0; i < 2; ++i) {                            \
      int c = (w << 1) + i;                                                    \
      gld_lds16(Kb + ((size_t)(kv0s + (c << 3) + lrow) << 6) + (cg << 3),      \
                kd + (c << 9));                                                \
      gld_lds16(Vtb + ((size_t)((c << 3) + lrow) << 10) + kv0s + (cg << 3),    \
                vd + (c << 9));                                                \
    }                                                                          \
  }

  STAGE(0, 0);
  __syncthreads();

  for (int t = 0; t < 16; ++t) {
    const int cur = t & 1;
    if (t < 15) STAGE(t + 1, cur ^ 1);
    const u16* kb_ = &kbuf[cur][0];
    const u16* vb_ = &vbuf[cur][0];
    const u64* mbt = mbb + (((size_t)t) << 10);
    // C-init from bitmask (exp2 domain: -8 unmasked / -30008 masked)
    f32x4 sacc[2][4];
#pragma unroll
    for (int m = 0; m < 2; ++m)
#pragma unroll
      for (int j = 0; j < 4; ++j) {
        u64 wb = mbt[q0 + (m << 4) + (l4 << 2) + j];
        unsigned int bits = (unsigned int)(wb >> p0);
        sacc[m][0][j] = (bits & 1u) ? FU : FM;
        sacc[m][1][j] = (bits & 16u) ? FU : FM;
        sacc[m][2][j] = (bits & 256u) ? FU : FM;
        sacc[m][3][j] = (bits & 4096u) ? FU : FM;
      }
    // QK^T
    __builtin_amdgcn_s_setprio(1);
#pragma unroll
    for (int ks = 0; ks < 2; ++ks) {
      const int kg = l4 + (ks << 2);
      bf16x8 kf[4];
#pragma unroll
      for (int fn = 0; fn < 4; ++fn) {
        int rk = (fn << 4) + lo;
        kf[fn] = *(const bf16x8*)(kb_ + (rk << 6) + ((kg ^ (rk & 7)) << 3));
      }
#pragma unroll
      for (int m = 0; m < 2; ++m)
#pragma unroll
        for (int fn = 0; fn < 4; ++fn)
          sacc[m][fn] = __builtin_amdgcn_mfma_f32_16x16x32_bf16(
              qf[m][ks], kf[fn], sacc[m][fn], 0, 0, 0);
    }
    __builtin_amdgcn_s_setprio(0);
    // P = exp2(s), pack to bf16, store to per-wave LDS
#pragma unroll
    for (int m = 0; m < 2; ++m)
#pragma unroll
      for (int fn = 0; fn < 4; ++fn)
#pragma unroll
        for (int j = 0; j < 4; ++j) {
          float p = exp2f(sacc[m][fn][j]);
          unsigned int u = __builtin_bit_cast(unsigned int, p);
          int prow = (m << 4) + (l4 << 2) + j;
          int pcol = (fn << 4) + lo;
          p_w[(prow << 6) + (pcol ^ ((prow & 7) << 3))] =
              (u16)((u + 0x8000u) >> 16);
        }
    // PV + ones-column rowsum
    __builtin_amdgcn_s_setprio(1);
#pragma unroll
    for (int ks = 0; ks < 2; ++ks) {
      const int kg = l4 + (ks << 2);
      bf16x8 pf[2], vf[4];
#pragma unroll
      for (int m = 0; m < 2; ++m) {
        int pr = (m << 4) + lo;
        pf[m] = *(const bf16x8*)(p_w + (pr << 6) + ((kg ^ (pr & 7)) << 3));
      }
#pragma unroll
      for (int fd = 0; fd < 4; ++fd) {
        int rd = (fd << 4) + lo;
        vf[fd] = *(const bf16x8*)(vb_ + (rd << 6) + ((kg ^ (rd & 7)) << 3));
      }
#pragma unroll
      for (int m = 0; m < 2; ++m) {
        osum[m] = __builtin_amdgcn_mfma_f32_16x16x32_bf16(
            pf[m], onesf, osum[m], 0, 0, 0);
#pragma unroll
        for (int fd = 0; fd < 4; ++fd)
          osoft[m][fd] = __builtin_amdgcn_mfma_f32_16x16x32_bf16(
              pf[m], vf[fd], osoft[m][fd], 0, 0, 0);
      }
    }
    __builtin_amdgcn_s_setprio(0);
    __syncthreads();
  }
  // epilogue
#pragma unroll
  for (int m = 0; m < 2; ++m) {
    f32x4 rl;
#pragma unroll
    for (int j = 0; j < 4; ++j) rl[j] = 1.0f / osum[m][j];
#pragma unroll
    for (int fd = 0; fd < 4; ++fd)
#pragma unroll
      for (int j = 0; j < 4; ++j) {
        int qrow = q0 + (m << 4) + (l4 << 2) + j;
        int e = (h << 6) + (fd << 4) + lo;
        size_t idx = (((size_t)(b * 1024 + qrow)) << 10) + e;
        float o = osoft[m][fd][j] * rl[j] + bf2f(xvg[idx]);
        xv[idx] = f2bf(o);
      }
  }
#undef STAGE
}

// ---------------------------------------------------------------------------
extern "C" void kernel_launch(void* const* d_in, const int* in_sizes, int n_in,
                              void* d_out, int out_size, void* d_ws, size_t ws_size,
                              hipStream_t stream) {
  (void)in_sizes; (void)n_in; (void)out_size; (void)ws_size;
  const float* x   = (const float*)d_in[0];
  const float* mask= (const float*)d_in[1];
  const float* gnn = (const float*)d_in[2];
  const float* Wq  = (const float*)d_in[3];
  const float* bq  = (const float*)d_in[4];
  const float* Wk  = (const float*)d_in[5];
  const float* bk  = (const float*)d_in[6];
  const float* Wv  = (const float*)d_in[7];
  const float* bv  = (const float*)d_in[8];
  const float* Wo  = (const float*)d_in[9];
  const float* bo  = (const float*)d_in[10];
  const float* g1  = (const float*)d_in[11];
  const float* b1  = (const float*)d_in[12];
  const float* g2  = (const float*)d_in[13];
  const float* b2  = (const float*)d_in[14];
  const float* W1  = (const float*)d_in[15];
  const float* bf1 = (const float*)d_in[16];
  const float* W2  = (const float*)d_in[17];
  const float* bf2 = (const float*)d_in[18];
  float* out = (float*)d_out;

  char* ws = (char*)d_ws;
  const size_t MB = 1024 * 1024;
  // layout (MB): 0-24 wt | 24-32 nx -> xvbuf -> hbuf | 32-40 Q | 40-48 K
  // | 48-56 Vt | 56-57 mb (bitmask) | 64-72 gnnbf -> x1b | 72-80 xvg
  // post-attn: ff1 32-64
  u16*  wt    = (u16*)(ws);
  u16*  nx    = (u16*)(ws + 24 * MB);
  u16*  xvbuf = (u16*)(ws + 24 * MB);
  u16*  hbuf  = (u16*)(ws + 24 * MB);
  u16*  qk    = (u16*)(ws + 32 * MB);
  u16*  vt    = (u16*)(ws + 48 * MB);
  u64*  mb    = (u64*)(ws + 56 * MB);
  u16*  gnnbf = (u16*)(ws + 64 * MB);
  u16*  x1b   = (u16*)(ws + 64 * MB);
  u16*  xvg   = (u16*)(ws + 72 * MB);
  u16*  ff1   = (u16*)(ws + 32 * MB);

  pre_kernel<<<20480, 256, 0, stream>>>(Wq, Wk, Wv, Wo, W1, W2, wt,
                                        x, g1, b1, nx, mask, gnn, mb, gnnbf);
  gemm_qkv<<<dim3(64, 8, 3), 256, 0, stream>>>(nx, wt, bq, bk, bv, qk, vt);
  gemm_gnnv<<<dim3(16, 8, 4), 256, 0, stream>>>(gnnbf, vt, xvg);
  attn_kernel<<<512, 256, 0, stream>>>(
      qk, qk + (size_t)4 * MB, vt, mb, xvg, xvbuf);
  gemm_wo<<<dim3(64, 8), 256, 0, stream>>>(xvbuf, wt + (size_t)3 * MB, bo, x, x1b);
  ln_kernel_b<<<4096, 256, 0, stream>>>(x1b, g2, b2, hbuf);
  gemm_w1<<<dim3(64, 32), 256, 0, stream>>>(hbuf, wt + (size_t)4 * MB, bf1, ff1);
  gemm_w2<<<dim3(64, 8), 256, 3 * 24576, stream>>>(ff1, wt + (size_t)8 * MB, bf2, x1b, out);
}